// Round 2
// baseline (1253.572 us; speedup 1.0000x reference)
//
#include <hip/hip_runtime.h>
#include <math.h>

#define NN 50000
#define NE 800000
#define ET (NE + NN)     // edges + self-loops
#define DF 101
#define NEG 0.2f

// ---- order-preserving float<->uint for atomic max (handles negatives) ----
__device__ __forceinline__ unsigned ordF(float f) {
    unsigned b = __float_as_uint(f);
    return (b & 0x80000000u) ? ~b : (b | 0x80000000u);
}
__device__ __forceinline__ float unordF(unsigned u) {
    unsigned b = (u & 0x80000000u) ? (u & 0x7FFFFFFFu) : ~u;
    return __uint_as_float(b);
}

// ---- h = x @ W (one row per block), fused alpha_s/alpha_d epilogue ----
__global__ __launch_bounds__(128) void gemm_attn(
    const float* __restrict__ x, const float* __restrict__ W,
    const float* __restrict__ a_src, const float* __restrict__ a_dst,
    float* __restrict__ h, float* __restrict__ alpha_s, float* __restrict__ alpha_d)
{
    const int row = blockIdx.x;
    const int col = threadIdx.x;
    __shared__ float xs[DF];
    if (col < DF) xs[col] = x[row * DF + col];
    __syncthreads();

    float acc = 0.f;
    if (col < DF) {
        #pragma unroll 4
        for (int k = 0; k < DF; ++k)
            acc = fmaf(xs[k], W[k * DF + col], acc);
        h[row * DF + col] = acc;
    }

    float ps = (col < DF) ? acc * a_src[col] : 0.f;
    float pd = (col < DF) ? acc * a_dst[col] : 0.f;
    #pragma unroll
    for (int off = 32; off; off >>= 1) {
        ps += __shfl_down(ps, off);
        pd += __shfl_down(pd, off);
    }
    __shared__ float r[4];
    if ((threadIdx.x & 63) == 0) {
        r[(threadIdx.x >> 6) * 2 + 0] = ps;
        r[(threadIdx.x >> 6) * 2 + 1] = pd;
    }
    __syncthreads();
    if (threadIdx.x == 0) {
        alpha_s[row] = r[0] + r[2];
        alpha_d[row] = r[1] + r[3];
    }
}

// ---- init output buffer to bias row (makes the +b free) ----
__global__ void init_out(float* __restrict__ out, const float* __restrict__ b) {
    int i = blockIdx.x * blockDim.x + threadIdx.x;
    if (i < NN * DF) out[i] = b[i % DF];
}

// ---- pass A: e = leakyrelu(alpha_s[src] + alpha_d[dst]); segment max ----
__global__ void edge_max(const int* __restrict__ ei,
                         const float* __restrict__ a_s, const float* __restrict__ a_d,
                         float* __restrict__ ebuf, unsigned* __restrict__ m)
{
    int i = blockIdx.x * blockDim.x + threadIdx.x;
    if (i >= ET) return;
    int s, d;
    if (i < NE) { s = ei[i]; d = ei[NE + i]; } else { s = d = i - NE; }
    float e = a_s[s] + a_d[d];
    e = e > 0.f ? e : NEG * e;
    ebuf[i] = e;
    atomicMax(&m[d], ordF(e));
}

// ---- pass B: w = exp(e - m[dst]); segment sum ----
__global__ void edge_expsum(const int* __restrict__ ei, const unsigned* __restrict__ m,
                            float* __restrict__ ebuf, float* __restrict__ z)
{
    int i = blockIdx.x * blockDim.x + threadIdx.x;
    if (i >= ET) return;
    int d = (i < NE) ? ei[NE + i] : (i - NE);
    float w = expf(ebuf[i] - unordF(m[d]));
    ebuf[i] = w;
    atomicAdd(&z[d], w);
}

// ---- pass C: out[dst] += h[src] * (w / z[dst]) — 128 threads per edge ----
__global__ __launch_bounds__(256) void edge_accum(
    const int* __restrict__ ei, const float* __restrict__ ebuf,
    const float* __restrict__ z, const float* __restrict__ h,
    float* __restrict__ out)
{
    int e = blockIdx.x * 2 + (threadIdx.x >> 7);
    int c = threadIdx.x & 127;
    if (e >= ET) return;
    int s, d;
    if (e < NE) { s = ei[e]; d = ei[NE + e]; } else { s = d = e - NE; }
    float coef = ebuf[e] / (z[d] + 1e-16f);
    if (c < DF) atomicAdd(&out[d * DF + c], h[s * DF + c] * coef);
}

static inline size_t alignup(size_t v) { return (v + 255) & ~size_t(255); }

extern "C" void kernel_launch(void* const* d_in, const int* in_sizes, int n_in,
                              void* d_out, int out_size, void* d_ws, size_t ws_size,
                              hipStream_t stream)
{
    const float* x    = (const float*)d_in[0];
    const int*   ei   = (const int*)  d_in[1];   // [2, NE]
    const float* Ws   = (const float*)d_in[2];   // [L, D, D]
    const float* a_s  = (const float*)d_in[3];   // [L, D]
    const float* a_d  = (const float*)d_in[4];   // [L, D]
    const float* bias = (const float*)d_in[5];   // [L, D]
    float* out = (float*)d_out;

    char* w = (char*)d_ws;
    float*    h    = (float*)w;    w += alignup((size_t)NN * DF * 4);
    float*    x1   = (float*)w;    w += alignup((size_t)NN * DF * 4);
    float*    ebuf = (float*)w;    w += alignup((size_t)ET * 4);
    float*    as_n = (float*)w;    w += alignup((size_t)NN * 4);
    float*    ad_n = (float*)w;    w += alignup((size_t)NN * 4);
    float*    z    = (float*)w;    w += alignup((size_t)NN * 4);
    unsigned* m    = (unsigned*)w; w += alignup((size_t)NN * 4);

    for (int l = 0; l < 2; ++l) {
        const float* cur = (l == 0) ? x : x1;
        float*       nxt = (l == 0) ? x1 : out;

        hipMemsetAsync(m, 0, (size_t)NN * 4, stream);
        hipMemsetAsync(z, 0, (size_t)NN * 4, stream);
        init_out<<<(NN * DF + 255) / 256, 256, 0, stream>>>(nxt, bias + l * DF);

        gemm_attn<<<NN, 128, 0, stream>>>(cur, Ws + l * DF * DF,
                                          a_s + l * DF, a_d + l * DF,
                                          h, as_n, ad_n);

        edge_max<<<(ET + 255) / 256, 256, 0, stream>>>(ei, as_n, ad_n, ebuf, m);
        edge_expsum<<<(ET + 255) / 256, 256, 0, stream>>>(ei, m, ebuf, z);
        edge_accum<<<(ET + 1) / 2, 256, 0, stream>>>(ei, ebuf, z, h, nxt);
    }
}

// Round 5
// 549.439 us; speedup vs baseline: 2.2815x; 2.2815x over previous
//
#include <hip/hip_runtime.h>
#include <math.h>

#define NN 50000
#define NE 800000
#define ET (NE + NN)     // edges + self-loops
#define DF 101
#define NEG 0.2f
#define MAXK 8           // supports degree up to 8*64=512 (Poisson(17) max ~45)

// ---- h = x @ W (one row per block), fused alpha_s/alpha_d epilogue ----
__global__ __launch_bounds__(128) void gemm_attn(
    const float* __restrict__ x, const float* __restrict__ W,
    const float* __restrict__ a_src, const float* __restrict__ a_dst,
    float* __restrict__ h, float* __restrict__ alpha_s, float* __restrict__ alpha_d)
{
    const int row = blockIdx.x;
    const int col = threadIdx.x;
    __shared__ float xs[DF];
    if (col < DF) xs[col] = x[row * DF + col];
    __syncthreads();

    float acc = 0.f;
    if (col < DF) {
        #pragma unroll 4
        for (int k = 0; k < DF; ++k)
            acc = fmaf(xs[k], W[k * DF + col], acc);
        h[row * DF + col] = acc;
    }

    float ps = (col < DF) ? acc * a_src[col] : 0.f;
    float pd = (col < DF) ? acc * a_dst[col] : 0.f;
    #pragma unroll
    for (int off = 32; off; off >>= 1) {
        ps += __shfl_down(ps, off);
        pd += __shfl_down(pd, off);
    }
    __shared__ float r[4];
    if ((threadIdx.x & 63) == 0) {
        r[(threadIdx.x >> 6) * 2 + 0] = ps;
        r[(threadIdx.x >> 6) * 2 + 1] = pd;
    }
    __syncthreads();
    if (threadIdx.x == 0) {
        alpha_s[row] = r[0] + r[2];
        alpha_d[row] = r[1] + r[3];
    }
}

// ================= CSR build (once per launch; reused by both layers) =======

__global__ void count_deg(const int* __restrict__ ei, int* __restrict__ deg) {
    int i = blockIdx.x * blockDim.x + threadIdx.x;
    if (i >= ET) return;
    int d = (i < NE) ? ei[NE + i] : (i - NE);
    atomicAdd(&deg[d], 1);
}

// block-local inclusive scan of deg -> part; block totals -> aux
__global__ __launch_bounds__(256) void scanA(const int* __restrict__ deg,
                                             int* __restrict__ part, int* __restrict__ aux) {
    __shared__ int sh[256];
    int t = threadIdx.x;
    int i = blockIdx.x * 256 + t;
    int v = (i < NN) ? deg[i] : 0;
    sh[t] = v; __syncthreads();
    #pragma unroll
    for (int off = 1; off < 256; off <<= 1) {
        int u = (t >= off) ? sh[t - off] : 0;
        __syncthreads();
        sh[t] += u;
        __syncthreads();
    }
    if (i < NN) part[i] = sh[t];
    if (t == 255) aux[blockIdx.x] = sh[255];
}

// exclusive scan of aux (NB <= 256) in one block
__global__ __launch_bounds__(256) void scanB(const int* __restrict__ aux,
                                             int* __restrict__ auxex, int nb) {
    __shared__ int sh[256];
    int t = threadIdx.x;
    int v = (t < nb) ? aux[t] : 0;
    sh[t] = v; __syncthreads();
    #pragma unroll
    for (int off = 1; off < 256; off <<= 1) {
        int u = (t >= off) ? sh[t - off] : 0;
        __syncthreads();
        sh[t] += u;
        __syncthreads();
    }
    if (t < nb) auxex[t] = sh[t] - v;
}

__global__ void scanC(const int* __restrict__ part, const int* __restrict__ auxex,
                      int* __restrict__ rowptr) {
    int i = blockIdx.x * blockDim.x + threadIdx.x;
    if (i == 0) rowptr[0] = 0;
    if (i < NN) rowptr[i + 1] = part[i] + auxex[i >> 8];
}

__global__ void scatter_edges(const int* __restrict__ ei, const int* __restrict__ rowptr,
                              int* __restrict__ cur, int* __restrict__ srclist) {
    int i = blockIdx.x * blockDim.x + threadIdx.x;
    if (i >= ET) return;
    int s, d;
    if (i < NE) { s = ei[i]; d = ei[NE + i]; } else { s = d = i - NE; }
    int pos = rowptr[d] + atomicAdd(&cur[d], 1);
    srclist[pos] = s;
}

// ========== fused softmax + aggregate: one wave per dst node ================
__global__ __launch_bounds__(256) void gat_agg(
    const int* __restrict__ rowptr, const int* __restrict__ srclist,
    const float* __restrict__ a_s, const float* __restrict__ a_d,
    const float* __restrict__ h, const float* __restrict__ bias,
    float* __restrict__ out)
{
    int d = blockIdx.x * 4 + (threadIdx.x >> 6);
    if (d >= NN) return;
    int lane = threadIdx.x & 63;
    int s0 = rowptr[d], s1 = rowptr[d + 1];
    float ad = a_d[d];

    // phase 1: e per edge (lane-parallel, statically-indexed regs), wave max
    float earr[MAXK];
    int mysrc[MAXK];
    float mymax = -INFINITY;
    #pragma unroll
    for (int k = 0; k < MAXK; ++k) {
        int j = s0 + lane + k * 64;
        if (j < s1) {
            int s = srclist[j];
            mysrc[k] = s;
            float e = a_s[s] + ad;
            e = e > 0.f ? e : NEG * e;
            earr[k] = e;
            mymax = fmaxf(mymax, e);
        }
    }
    #pragma unroll
    for (int off = 32; off; off >>= 1)
        mymax = fmaxf(mymax, __shfl_xor(mymax, off));

    // phase 2: w = exp(e - m), wave sum
    float sum = 0.f;
    #pragma unroll
    for (int k = 0; k < MAXK; ++k) {
        int j = s0 + lane + k * 64;
        if (j < s1) {
            float w = __expf(earr[k] - mymax);
            earr[k] = w;
            sum += w;
        }
    }
    #pragma unroll
    for (int off = 32; off; off >>= 1)
        sum += __shfl_xor(sum, off);
    float invz = 1.f / (sum + 1e-16f);

    // phase 3: serial over edges, 64 lanes over 101 cols (2 cols/lane)
    float acc0 = 0.f, acc1 = 0.f;
    #pragma unroll
    for (int k = 0; k < MAXK; ++k) {
        int jb = s0 + k * 64;
        if (jb < s1) {
            float w = earr[k];
            int   ms = mysrc[k];
            int lim = s1 - jb; if (lim > 64) lim = 64;
            for (int who = 0; who < lim; ++who) {
                float coef = __shfl(w, who) * invz;
                int   src  = __shfl(ms, who);
                const float* hr = h + (size_t)src * DF;
                acc0 += coef * hr[lane];
                acc1 += coef * hr[64 + lane];   // lanes >=37 read next row; masked at write
            }
        }
    }
    out[(size_t)d * DF + lane] = acc0 + bias[lane];
    if (lane < DF - 64)
        out[(size_t)d * DF + 64 + lane] = acc1 + bias[64 + lane];
}

static inline size_t alignup(size_t v) { return (v + 255) & ~size_t(255); }

extern "C" void kernel_launch(void* const* d_in, const int* in_sizes, int n_in,
                              void* d_out, int out_size, void* d_ws, size_t ws_size,
                              hipStream_t stream)
{
    const float* x    = (const float*)d_in[0];
    const int*   ei   = (const int*)  d_in[1];   // [2, NE]
    const float* Ws   = (const float*)d_in[2];   // [L, D, D]
    const float* a_s  = (const float*)d_in[3];   // [L, D]
    const float* a_d  = (const float*)d_in[4];   // [L, D]
    const float* bias = (const float*)d_in[5];   // [L, D]
    float* out = (float*)d_out;

    char* w = (char*)d_ws;
    float* h       = (float*)w; w += alignup((size_t)NN * DF * 4);
    float* x1      = (float*)w; w += alignup((size_t)NN * DF * 4);
    int*   srclist = (int*)w;   w += alignup((size_t)ET * 4);
    float* as_n    = (float*)w; w += alignup((size_t)NN * 4);
    float* ad_n    = (float*)w; w += alignup((size_t)NN * 4);
    int*   deg     = (int*)w;   w += alignup((size_t)NN * 4);
    int*   part    = (int*)w;   w += alignup((size_t)NN * 4);
    int*   cur     = (int*)w;   w += alignup((size_t)NN * 4);
    int*   rowptr  = (int*)w;   w += alignup((size_t)(NN + 1) * 4);
    int*   aux     = (int*)w;   w += alignup(256 * 4);
    int*   auxex   = (int*)w;   w += alignup(256 * 4);

    const int NB = (NN + 255) / 256;   // 196 scan blocks

    // ---- build CSR (dst-bucketed) once; graph identical for both layers ----
    hipMemsetAsync(deg, 0, (size_t)NN * 4, stream);
    hipMemsetAsync(cur, 0, (size_t)NN * 4, stream);
    count_deg<<<(ET + 255) / 256, 256, 0, stream>>>(ei, deg);
    scanA<<<NB, 256, 0, stream>>>(deg, part, aux);
    scanB<<<1, 256, 0, stream>>>(aux, auxex, NB);
    scanC<<<NB, 256, 0, stream>>>(part, auxex, rowptr);
    scatter_edges<<<(ET + 255) / 256, 256, 0, stream>>>(ei, rowptr, cur, srclist);

    for (int l = 0; l < 2; ++l) {
        const float* curx = (l == 0) ? x : x1;
        float*       nxt  = (l == 0) ? x1 : out;

        gemm_attn<<<NN, 128, 0, stream>>>(curx, Ws + l * DF * DF,
                                          a_s + l * DF, a_d + l * DF,
                                          h, as_n, ad_n);

        gat_agg<<<(NN + 3) / 4, 256, 0, stream>>>(rowptr, srclist, as_n, ad_n,
                                                  h, bias + l * DF, nxt);
    }
}

// Round 6
// 455.054 us; speedup vs baseline: 2.7548x; 1.2074x over previous
//
#include <hip/hip_runtime.h>
#include <math.h>

#define NN 50000
#define NE 800000
#define ET (NE + NN)     // edges + self-loops
#define DF 101
#define NEG 0.2f
#define MAXK 8           // gat_agg: supports in-degree up to 8*64=512
#define BM 32            // gemm rows per block

// ---- h = x @ W, register-tiled: thread=col, BM rows in regs ----
// x-tile staged transposed in LDS -> float4 broadcast reads; W via L1/L2.
__global__ __launch_bounds__(128) void gemm_attn(
    const float* __restrict__ x, const float* __restrict__ W,
    const float* __restrict__ a_src, const float* __restrict__ a_dst,
    float* __restrict__ h, float* __restrict__ alpha_s, float* __restrict__ alpha_d)
{
    __shared__ float xt[DF][BM + 4];       // [k][r], stride 36 f32 (16B aligned)
    __shared__ float red[2][BM][2];
    const int t    = threadIdx.x;          // 0..127
    const int col  = t;
    const int row0 = blockIdx.x * BM;

    // stage x tile transposed; lanes = k (coalesced global read)
    if (t < DF) {
        #pragma unroll
        for (int r = 0; r < BM; ++r)
            xt[t][r] = (row0 + r < NN) ? x[(size_t)(row0 + r) * DF + t] : 0.f;
    }
    __syncthreads();

    float acc[BM];
    #pragma unroll
    for (int r = 0; r < BM; ++r) acc[r] = 0.f;

    for (int k = 0; k < DF; ++k) {
        float wv = (col < DF) ? W[k * DF + col] : 0.f;
        const float4* xk = (const float4*)xt[k];
        #pragma unroll
        for (int r4 = 0; r4 < BM / 4; ++r4) {
            float4 xv = xk[r4];            // same addr all lanes -> LDS broadcast
            acc[r4 * 4 + 0] = fmaf(xv.x, wv, acc[r4 * 4 + 0]);
            acc[r4 * 4 + 1] = fmaf(xv.y, wv, acc[r4 * 4 + 1]);
            acc[r4 * 4 + 2] = fmaf(xv.z, wv, acc[r4 * 4 + 2]);
            acc[r4 * 4 + 3] = fmaf(xv.w, wv, acc[r4 * 4 + 3]);
        }
    }

    // write h + fused alpha reductions
    const float asv = (col < DF) ? a_src[col] : 0.f;
    const float adv = (col < DF) ? a_dst[col] : 0.f;
    const int wave = t >> 6, lane = t & 63;
    #pragma unroll
    for (int r = 0; r < BM; ++r) {
        if (col < DF && row0 + r < NN)
            h[(size_t)(row0 + r) * DF + col] = acc[r];
        float ps = acc[r] * asv;
        float pd = acc[r] * adv;
        #pragma unroll
        for (int off = 32; off; off >>= 1) {
            ps += __shfl_xor(ps, off);
            pd += __shfl_xor(pd, off);
        }
        if (lane == 0) { red[wave][r][0] = ps; red[wave][r][1] = pd; }
    }
    __syncthreads();
    if (t < BM && row0 + t < NN) {
        alpha_s[row0 + t] = red[0][t][0] + red[1][t][0];
        alpha_d[row0 + t] = red[0][t][1] + red[1][t][1];
    }
}

// ================= CSR build (once per launch; reused by both layers) =======

__global__ void count_deg(const int* __restrict__ ei, int* __restrict__ deg) {
    int i = blockIdx.x * blockDim.x + threadIdx.x;
    if (i >= ET) return;
    int d = (i < NE) ? ei[NE + i] : (i - NE);
    atomicAdd(&deg[d], 1);
}

__global__ __launch_bounds__(256) void scanA(const int* __restrict__ deg,
                                             int* __restrict__ part, int* __restrict__ aux) {
    __shared__ int sh[256];
    int t = threadIdx.x;
    int i = blockIdx.x * 256 + t;
    int v = (i < NN) ? deg[i] : 0;
    sh[t] = v; __syncthreads();
    #pragma unroll
    for (int off = 1; off < 256; off <<= 1) {
        int u = (t >= off) ? sh[t - off] : 0;
        __syncthreads();
        sh[t] += u;
        __syncthreads();
    }
    if (i < NN) part[i] = sh[t];
    if (t == 255) aux[blockIdx.x] = sh[255];
}

__global__ __launch_bounds__(256) void scanB(const int* __restrict__ aux,
                                             int* __restrict__ auxex, int nb) {
    __shared__ int sh[256];
    int t = threadIdx.x;
    int v = (t < nb) ? aux[t] : 0;
    sh[t] = v; __syncthreads();
    #pragma unroll
    for (int off = 1; off < 256; off <<= 1) {
        int u = (t >= off) ? sh[t - off] : 0;
        __syncthreads();
        sh[t] += u;
        __syncthreads();
    }
    if (t < nb) auxex[t] = sh[t] - v;
}

__global__ void scanC(const int* __restrict__ part, const int* __restrict__ auxex,
                      int* __restrict__ rowptr) {
    int i = blockIdx.x * blockDim.x + threadIdx.x;
    if (i == 0) rowptr[0] = 0;
    if (i < NN) rowptr[i + 1] = part[i] + auxex[i >> 8];
}

__global__ void scatter_edges(const int* __restrict__ ei, const int* __restrict__ rowptr,
                              int* __restrict__ cur, int* __restrict__ srclist) {
    int i = blockIdx.x * blockDim.x + threadIdx.x;
    if (i >= ET) return;
    int s, d;
    if (i < NE) { s = ei[i]; d = ei[NE + i]; } else { s = d = i - NE; }
    int pos = rowptr[d] + atomicAdd(&cur[d], 1);
    srclist[pos] = s;
}

// ========== fused softmax + aggregate: one wave per dst node ================
__global__ __launch_bounds__(256) void gat_agg(
    const int* __restrict__ rowptr, const int* __restrict__ srclist,
    const float* __restrict__ a_s, const float* __restrict__ a_d,
    const float* __restrict__ h, const float* __restrict__ bias,
    float* __restrict__ out)
{
    int d = blockIdx.x * 4 + (threadIdx.x >> 6);
    if (d >= NN) return;
    int lane = threadIdx.x & 63;
    int s0 = rowptr[d], s1 = rowptr[d + 1];
    float ad = a_d[d];

    float earr[MAXK];
    int mysrc[MAXK];
    float mymax = -INFINITY;
    #pragma unroll
    for (int k = 0; k < MAXK; ++k) {
        int j = s0 + lane + k * 64;
        if (j < s1) {
            int s = srclist[j];
            mysrc[k] = s;
            float e = a_s[s] + ad;
            e = e > 0.f ? e : NEG * e;
            earr[k] = e;
            mymax = fmaxf(mymax, e);
        }
    }
    #pragma unroll
    for (int off = 32; off; off >>= 1)
        mymax = fmaxf(mymax, __shfl_xor(mymax, off));

    float sum = 0.f;
    #pragma unroll
    for (int k = 0; k < MAXK; ++k) {
        int j = s0 + lane + k * 64;
        if (j < s1) {
            float w = __expf(earr[k] - mymax);
            earr[k] = w;
            sum += w;
        }
    }
    #pragma unroll
    for (int off = 32; off; off >>= 1)
        sum += __shfl_xor(sum, off);
    float invz = 1.f / (sum + 1e-16f);

    float acc0 = 0.f, acc1 = 0.f;
    #pragma unroll
    for (int k = 0; k < MAXK; ++k) {
        int jb = s0 + k * 64;
        if (jb < s1) {
            float w = earr[k];
            int   ms = mysrc[k];
            int lim = s1 - jb; if (lim > 64) lim = 64;
            for (int who = 0; who < lim; ++who) {
                float coef = __shfl(w, who) * invz;
                int   src  = __shfl(ms, who);
                const float* hr = h + (size_t)src * DF;
                acc0 += coef * hr[lane];
                acc1 += coef * hr[64 + lane];   // lanes >=37 read next row; masked at write
            }
        }
    }
    out[(size_t)d * DF + lane] = acc0 + bias[lane];
    if (lane < DF - 64)
        out[(size_t)d * DF + 64 + lane] = acc1 + bias[64 + lane];
}

static inline size_t alignup(size_t v) { return (v + 255) & ~size_t(255); }

extern "C" void kernel_launch(void* const* d_in, const int* in_sizes, int n_in,
                              void* d_out, int out_size, void* d_ws, size_t ws_size,
                              hipStream_t stream)
{
    const float* x    = (const float*)d_in[0];
    const int*   ei   = (const int*)  d_in[1];   // [2, NE]
    const float* Ws   = (const float*)d_in[2];   // [L, D, D]
    const float* a_s  = (const float*)d_in[3];   // [L, D]
    const float* a_d  = (const float*)d_in[4];   // [L, D]
    const float* bias = (const float*)d_in[5];   // [L, D]
    float* out = (float*)d_out;

    char* w = (char*)d_ws;
    float* h       = (float*)w; w += alignup((size_t)NN * DF * 4);
    float* x1      = (float*)w; w += alignup((size_t)NN * DF * 4);
    int*   srclist = (int*)w;   w += alignup((size_t)ET * 4);
    float* as_n    = (float*)w; w += alignup((size_t)NN * 4);
    float* ad_n    = (float*)w; w += alignup((size_t)NN * 4);
    int*   deg     = (int*)w;   w += alignup((size_t)NN * 4);
    int*   part    = (int*)w;   w += alignup((size_t)NN * 4);
    int*   cur     = (int*)w;   w += alignup((size_t)NN * 4);
    int*   rowptr  = (int*)w;   w += alignup((size_t)(NN + 1) * 4);
    int*   aux     = (int*)w;   w += alignup(256 * 4);
    int*   auxex   = (int*)w;   w += alignup(256 * 4);

    const int NB = (NN + 255) / 256;   // 196 scan blocks

    hipMemsetAsync(deg, 0, (size_t)NN * 4, stream);
    hipMemsetAsync(cur, 0, (size_t)NN * 4, stream);
    count_deg<<<(ET + 255) / 256, 256, 0, stream>>>(ei, deg);
    scanA<<<NB, 256, 0, stream>>>(deg, part, aux);
    scanB<<<1, 256, 0, stream>>>(aux, auxex, NB);
    scanC<<<NB, 256, 0, stream>>>(part, auxex, rowptr);
    scatter_edges<<<(ET + 255) / 256, 256, 0, stream>>>(ei, rowptr, cur, srclist);

    for (int l = 0; l < 2; ++l) {
        const float* curx = (l == 0) ? x : x1;
        float*       nxt  = (l == 0) ? x1 : out;

        gemm_attn<<<(NN + BM - 1) / BM, 128, 0, stream>>>(
            curx, Ws + l * DF * DF, a_s + l * DF, a_d + l * DF, h, as_n, ad_n);

        gat_agg<<<(NN + 3) / 4, 256, 0, stream>>>(rowptr, srclist, as_n, ad_n,
                                                  h, bias + l * DF, nxt);
    }
}

// Round 7
// 395.195 us; speedup vs baseline: 3.1720x; 1.1515x over previous
//
#include <hip/hip_runtime.h>
#include <math.h>

#define NN 50000
#define NE 800000
#define ET (NE + NN)     // edges + self-loops
#define DF 101
#define HP 104           // padded bf16 row stride (52 uints, 4B-aligned)
#define NEG 0.2f
#define MAXK 8           // gat_agg: supports in-degree up to 8*64=512
#define BM 32            // gemm rows per block

// float -> bf16 round-to-nearest-even
__device__ __forceinline__ unsigned short f2bf(float f) {
    unsigned u = __float_as_uint(f);
    unsigned r = u + 0x7FFFu + ((u >> 16) & 1u);
    return (unsigned short)(r >> 16);
}

// ---- wa = W @ a  (per-layer, 101-vectors); wave per output row k ----
__global__ __launch_bounds__(256) void proj_a(
    const float* __restrict__ W, const float* __restrict__ a_s,
    const float* __restrict__ a_d,
    float* __restrict__ wa_s, float* __restrict__ wa_d)
{
    int k = blockIdx.x * 4 + (threadIdx.x >> 6);
    if (k >= DF) return;
    int lane = threadIdx.x & 63;
    const float* wr = W + (size_t)k * DF;
    float w0 = wr[lane];
    float w1 = (lane < DF - 64) ? wr[64 + lane] : 0.f;
    float s1 = (lane < DF - 64) ? a_s[64 + lane] : 0.f;
    float d1 = (lane < DF - 64) ? a_d[64 + lane] : 0.f;
    float ps = w0 * a_s[lane] + w1 * s1;
    float pd = w0 * a_d[lane] + w1 * d1;
    #pragma unroll
    for (int off = 32; off; off >>= 1) {
        ps += __shfl_xor(ps, off);
        pd += __shfl_xor(pd, off);
    }
    if (lane == 0) { wa_s[k] = ps; wa_d[k] = pd; }
}

// ---- alpha_s[n] = x[n]·wa_s, alpha_d[n] = x[n]·wa_d; wave per node ----
__global__ __launch_bounds__(256) void alpha_n(
    const float* __restrict__ x, const float* __restrict__ wa_s,
    const float* __restrict__ wa_d,
    float* __restrict__ as_n, float* __restrict__ ad_n)
{
    int n = blockIdx.x * 4 + (threadIdx.x >> 6);
    if (n >= NN) return;
    int lane = threadIdx.x & 63;
    const float* xr = x + (size_t)n * DF;
    float x0 = xr[lane];
    float x1v = (lane < DF - 64) ? xr[64 + lane] : 0.f;
    float s1  = (lane < DF - 64) ? wa_s[64 + lane] : 0.f;
    float d1  = (lane < DF - 64) ? wa_d[64 + lane] : 0.f;
    float ps = x0 * wa_s[lane] + x1v * s1;
    float pd = x0 * wa_d[lane] + x1v * d1;
    #pragma unroll
    for (int off = 32; off; off >>= 1) {
        ps += __shfl_xor(ps, off);
        pd += __shfl_xor(pd, off);
    }
    if (lane == 0) { as_n[n] = ps; ad_n[n] = pd; }
}

// ---- h16 = bf16(x @ W): 256 thr, thread = (col, row-half), 16 rows/thread --
__global__ __launch_bounds__(256) void gemm_h(
    const float* __restrict__ x, const float* __restrict__ W,
    unsigned short* __restrict__ h16)
{
    __shared__ float xt[DF][BM + 4];       // [k][r], stride 36 f32 (16B-aligned rows)
    const int t    = threadIdx.x;
    const int col  = t & 127;
    const int rg   = t >> 7;               // row half: 0 -> rows 0..15, 1 -> 16..31
    const int row0 = blockIdx.x * BM;

    if (t < DF) {
        #pragma unroll
        for (int r = 0; r < BM; ++r)
            xt[t][r] = (row0 + r < NN) ? x[(size_t)(row0 + r) * DF + t] : 0.f;
    }
    __syncthreads();

    float acc[16];
    #pragma unroll
    for (int r = 0; r < 16; ++r) acc[r] = 0.f;

    for (int k = 0; k < DF; ++k) {
        float wv = (col < DF) ? W[k * DF + col] : 0.f;
        const float4* xk = (const float4*)xt[k];
        #pragma unroll
        for (int j = 0; j < 4; ++j) {
            float4 xv = xk[rg * 4 + j];    // broadcast (same addr across lanes)
            acc[j * 4 + 0] = fmaf(xv.x, wv, acc[j * 4 + 0]);
            acc[j * 4 + 1] = fmaf(xv.y, wv, acc[j * 4 + 1]);
            acc[j * 4 + 2] = fmaf(xv.z, wv, acc[j * 4 + 2]);
            acc[j * 4 + 3] = fmaf(xv.w, wv, acc[j * 4 + 3]);
        }
    }

    #pragma unroll
    for (int r = 0; r < 16; ++r) {
        int row = row0 + rg * 16 + r;
        if (row < NN) {
            if (col < DF)      h16[(size_t)row * HP + col] = f2bf(acc[r]);
            else if (col < HP) h16[(size_t)row * HP + col] = 0;  // zero pads
        }
    }
}

// ================= CSR build (once per launch; reused by both layers) =======

__global__ void count_deg(const int* __restrict__ ei, int* __restrict__ deg) {
    int i = blockIdx.x * blockDim.x + threadIdx.x;
    if (i >= ET) return;
    int d = (i < NE) ? ei[NE + i] : (i - NE);
    atomicAdd(&deg[d], 1);
}

__global__ __launch_bounds__(256) void scanA(const int* __restrict__ deg,
                                             int* __restrict__ part, int* __restrict__ aux) {
    __shared__ int sh[256];
    int t = threadIdx.x;
    int i = blockIdx.x * 256 + t;
    int v = (i < NN) ? deg[i] : 0;
    sh[t] = v; __syncthreads();
    #pragma unroll
    for (int off = 1; off < 256; off <<= 1) {
        int u = (t >= off) ? sh[t - off] : 0;
        __syncthreads();
        sh[t] += u;
        __syncthreads();
    }
    if (i < NN) part[i] = sh[t];
    if (t == 255) aux[blockIdx.x] = sh[255];
}

__global__ __launch_bounds__(256) void scanB(const int* __restrict__ aux,
                                             int* __restrict__ auxex, int nb) {
    __shared__ int sh[256];
    int t = threadIdx.x;
    int v = (t < nb) ? aux[t] : 0;
    sh[t] = v; __syncthreads();
    #pragma unroll
    for (int off = 1; off < 256; off <<= 1) {
        int u = (t >= off) ? sh[t - off] : 0;
        __syncthreads();
        sh[t] += u;
        __syncthreads();
    }
    if (t < nb) auxex[t] = sh[t] - v;
}

__global__ void scanC(const int* __restrict__ part, const int* __restrict__ auxex,
                      int* __restrict__ rowptr) {
    int i = blockIdx.x * blockDim.x + threadIdx.x;
    if (i == 0) rowptr[0] = 0;
    if (i < NN) rowptr[i + 1] = part[i] + auxex[i >> 8];
}

__global__ void scatter_edges(const int* __restrict__ ei, const int* __restrict__ rowptr,
                              int* __restrict__ cur, int* __restrict__ srclist) {
    int i = blockIdx.x * blockDim.x + threadIdx.x;
    if (i >= ET) return;
    int s, d;
    if (i < NE) { s = ei[i]; d = ei[NE + i]; } else { s = d = i - NE; }
    int pos = rowptr[d] + atomicAdd(&cur[d], 1);
    srclist[pos] = s;
}

// ========== fused softmax + aggregate (bf16 h gather): wave per dst =========
__global__ __launch_bounds__(256) void gat_agg(
    const int* __restrict__ rowptr, const int* __restrict__ srclist,
    const float* __restrict__ a_s, const float* __restrict__ a_d,
    const unsigned short* __restrict__ h16, const float* __restrict__ bias,
    float* __restrict__ out)
{
    int d = blockIdx.x * 4 + (threadIdx.x >> 6);
    if (d >= NN) return;
    int lane = threadIdx.x & 63;
    int s0 = rowptr[d], s1 = rowptr[d + 1];
    float ad = a_d[d];

    float earr[MAXK];
    int mysrc[MAXK];
    float mymax = -INFINITY;
    #pragma unroll
    for (int k = 0; k < MAXK; ++k) {
        int j = s0 + lane + k * 64;
        if (j < s1) {
            int s = srclist[j];
            mysrc[k] = s;
            float e = a_s[s] + ad;
            e = e > 0.f ? e : NEG * e;
            earr[k] = e;
            mymax = fmaxf(mymax, e);
        }
    }
    #pragma unroll
    for (int off = 32; off; off >>= 1)
        mymax = fmaxf(mymax, __shfl_xor(mymax, off));

    float sum = 0.f;
    #pragma unroll
    for (int k = 0; k < MAXK; ++k) {
        int j = s0 + lane + k * 64;
        if (j < s1) {
            float w = __expf(earr[k] - mymax);
            earr[k] = w;
            sum += w;
        }
    }
    #pragma unroll
    for (int off = 32; off; off >>= 1)
        sum += __shfl_xor(sum, off);
    float invz = 1.f / (sum + 1e-16f);

    // serial over edges; lane reads one uint = 2 bf16 cols (2*li, 2*li+1)
    const int li = (lane < 51) ? lane : 51;   // lanes >=52 read pad zeros
    float acc0 = 0.f, acc1 = 0.f;
    #pragma unroll
    for (int k = 0; k < MAXK; ++k) {
        int jb = s0 + k * 64;
        if (jb < s1) {
            float w = earr[k];
            int   ms = mysrc[k];
            int lim = s1 - jb; if (lim > 64) lim = 64;
            for (int who = 0; who < lim; ++who) {
                float coef = __shfl(w, who) * invz;
                int   src  = __shfl(ms, who);
                unsigned v = *((const unsigned*)(h16 + (size_t)src * HP) + li);
                float f0 = __uint_as_float((v & 0x0000FFFFu) << 16);
                float f1 = __uint_as_float(v & 0xFFFF0000u);
                acc0 = fmaf(coef, f0, acc0);
                acc1 = fmaf(coef, f1, acc1);
            }
        }
    }
    int c0 = 2 * lane;
    if (c0 < DF)     out[(size_t)d * DF + c0]     = acc0 + bias[c0];
    if (c0 + 1 < DF) out[(size_t)d * DF + c0 + 1] = acc1 + bias[c0 + 1];
}

static inline size_t alignup(size_t v) { return (v + 255) & ~size_t(255); }

extern "C" void kernel_launch(void* const* d_in, const int* in_sizes, int n_in,
                              void* d_out, int out_size, void* d_ws, size_t ws_size,
                              hipStream_t stream)
{
    const float* x    = (const float*)d_in[0];
    const int*   ei   = (const int*)  d_in[1];   // [2, NE]
    const float* Ws   = (const float*)d_in[2];   // [L, D, D]
    const float* a_s  = (const float*)d_in[3];   // [L, D]
    const float* a_d  = (const float*)d_in[4];   // [L, D]
    const float* bias = (const float*)d_in[5];   // [L, D]
    float* out = (float*)d_out;

    char* w = (char*)d_ws;
    unsigned short* h16 = (unsigned short*)w; w += alignup((size_t)NN * HP * 2);
    float* x1      = (float*)w; w += alignup((size_t)NN * DF * 4);
    int*   srclist = (int*)w;   w += alignup((size_t)ET * 4);
    float* as_n    = (float*)w; w += alignup((size_t)NN * 4);
    float* ad_n    = (float*)w; w += alignup((size_t)NN * 4);
    int*   deg     = (int*)w;   w += alignup((size_t)NN * 4);
    int*   part    = (int*)w;   w += alignup((size_t)NN * 4);
    int*   cur     = (int*)w;   w += alignup((size_t)NN * 4);
    int*   rowptr  = (int*)w;   w += alignup((size_t)(NN + 1) * 4);
    int*   aux     = (int*)w;   w += alignup(256 * 4);
    int*   auxex   = (int*)w;   w += alignup(256 * 4);
    float* wa_s    = (float*)w; w += alignup(DF * 4);
    float* wa_d    = (float*)w; w += alignup(DF * 4);

    const int NB = (NN + 255) / 256;   // 196 scan blocks

    hipMemsetAsync(deg, 0, (size_t)NN * 4, stream);
    hipMemsetAsync(cur, 0, (size_t)NN * 4, stream);
    count_deg<<<(ET + 255) / 256, 256, 0, stream>>>(ei, deg);
    scanA<<<NB, 256, 0, stream>>>(deg, part, aux);
    scanB<<<1, 256, 0, stream>>>(aux, auxex, NB);
    scanC<<<NB, 256, 0, stream>>>(part, auxex, rowptr);
    scatter_edges<<<(ET + 255) / 256, 256, 0, stream>>>(ei, rowptr, cur, srclist);

    for (int l = 0; l < 2; ++l) {
        const float* curx = (l == 0) ? x : x1;
        float*       nxt  = (l == 0) ? x1 : out;
        const float* Wl   = Ws + l * DF * DF;

        proj_a<<<(DF + 3) / 4, 256, 0, stream>>>(Wl, a_s + l * DF, a_d + l * DF,
                                                 wa_s, wa_d);
        alpha_n<<<(NN + 3) / 4, 256, 0, stream>>>(curx, wa_s, wa_d, as_n, ad_n);
        gemm_h<<<(NN + BM - 1) / BM, 256, 0, stream>>>(curx, Wl, h16);
        gat_agg<<<(NN + 3) / 4, 256, 0, stream>>>(rowptr, srclist, as_n, ad_n,
                                                  h16, bias + l * DF, nxt);
    }
}

// Round 8
// 352.762 us; speedup vs baseline: 3.5536x; 1.1203x over previous
//
#include <hip/hip_runtime.h>
#include <math.h>

#define NN 50000
#define NE 800000
#define ET (NE + NN)     // edges + self-loops
#define DF 101
#define HP 104           // padded bf16 row stride (52 uints, 4B-aligned)
#define NEG 0.2f
#define MAXK 8           // gat_agg: supports in-degree up to 8*64=512
#define BM 32            // gemm rows per block

// float -> bf16 round-to-nearest-even
__device__ __forceinline__ unsigned short f2bf(float f) {
    unsigned u = __float_as_uint(f);
    unsigned r = u + 0x7FFFu + ((u >> 16) & 1u);
    return (unsigned short)(r >> 16);
}
__device__ __forceinline__ float bflo(unsigned v) { return __uint_as_float(v << 16); }
__device__ __forceinline__ float bfhi(unsigned v) { return __uint_as_float(v & 0xFFFF0000u); }

// ---- wa = W @ a  (per-layer, 101-vectors); wave per output row k ----
__global__ __launch_bounds__(256) void proj_a(
    const float* __restrict__ W, const float* __restrict__ a_s,
    const float* __restrict__ a_d,
    float* __restrict__ wa_s, float* __restrict__ wa_d)
{
    int k = blockIdx.x * 4 + (threadIdx.x >> 6);
    if (k >= DF) return;
    int lane = threadIdx.x & 63;
    const float* wr = W + (size_t)k * DF;
    float w0 = wr[lane];
    float w1 = (lane < DF - 64) ? wr[64 + lane] : 0.f;
    float s1 = (lane < DF - 64) ? a_s[64 + lane] : 0.f;
    float d1 = (lane < DF - 64) ? a_d[64 + lane] : 0.f;
    float ps = w0 * a_s[lane] + w1 * s1;
    float pd = w0 * a_d[lane] + w1 * d1;
    #pragma unroll
    for (int off = 32; off; off >>= 1) {
        ps += __shfl_xor(ps, off);
        pd += __shfl_xor(pd, off);
    }
    if (lane == 0) { wa_s[k] = ps; wa_d[k] = pd; }
}

// ---- alpha_s[n] = x[n]·wa_s, alpha_d[n] = x[n]·wa_d; wave per node ----
__global__ __launch_bounds__(256) void alpha_n(
    const float* __restrict__ x, const float* __restrict__ wa_s,
    const float* __restrict__ wa_d,
    float* __restrict__ as_n, float* __restrict__ ad_n)
{
    int n = blockIdx.x * 4 + (threadIdx.x >> 6);
    if (n >= NN) return;
    int lane = threadIdx.x & 63;
    const float* xr = x + (size_t)n * DF;
    float x0 = xr[lane];
    float x1v = (lane < DF - 64) ? xr[64 + lane] : 0.f;
    float s1  = (lane < DF - 64) ? wa_s[64 + lane] : 0.f;
    float d1  = (lane < DF - 64) ? wa_d[64 + lane] : 0.f;
    float ps = x0 * wa_s[lane] + x1v * s1;
    float pd = x0 * wa_d[lane] + x1v * d1;
    #pragma unroll
    for (int off = 32; off; off >>= 1) {
        ps += __shfl_xor(ps, off);
        pd += __shfl_xor(pd, off);
    }
    if (lane == 0) { as_n[n] = ps; ad_n[n] = pd; }
}

// ---- h16 = bf16(x @ W): 256 thr, thread = (col, row-half), 16 rows/thread --
__global__ __launch_bounds__(256) void gemm_h(
    const float* __restrict__ x, const float* __restrict__ W,
    unsigned short* __restrict__ h16)
{
    __shared__ float xt[DF][BM + 4];       // [k][r], stride 36 f32 (16B-aligned rows)
    const int t    = threadIdx.x;
    const int col  = t & 127;
    const int rg   = t >> 7;               // row half: 0 -> rows 0..15, 1 -> 16..31
    const int row0 = blockIdx.x * BM;

    if (t < DF) {
        #pragma unroll
        for (int r = 0; r < BM; ++r)
            xt[t][r] = (row0 + r < NN) ? x[(size_t)(row0 + r) * DF + t] : 0.f;
    }
    __syncthreads();

    float acc[16];
    #pragma unroll
    for (int r = 0; r < 16; ++r) acc[r] = 0.f;

    for (int k = 0; k < DF; ++k) {
        float wv = (col < DF) ? W[k * DF + col] : 0.f;
        const float4* xk = (const float4*)xt[k];
        #pragma unroll
        for (int j = 0; j < 4; ++j) {
            float4 xv = xk[rg * 4 + j];    // broadcast (same addr across lanes)
            acc[j * 4 + 0] = fmaf(xv.x, wv, acc[j * 4 + 0]);
            acc[j * 4 + 1] = fmaf(xv.y, wv, acc[j * 4 + 1]);
            acc[j * 4 + 2] = fmaf(xv.z, wv, acc[j * 4 + 2]);
            acc[j * 4 + 3] = fmaf(xv.w, wv, acc[j * 4 + 3]);
        }
    }

    #pragma unroll
    for (int r = 0; r < 16; ++r) {
        int row = row0 + rg * 16 + r;
        if (row < NN) {
            if (col < DF)      h16[(size_t)row * HP + col] = f2bf(acc[r]);
            else if (col < HP) h16[(size_t)row * HP + col] = 0;  // zero pads
        }
    }
}

// ================= CSR build (once per launch; reused by both layers) =======

__global__ void count_deg(const int* __restrict__ ei, int* __restrict__ deg) {
    int i = blockIdx.x * blockDim.x + threadIdx.x;
    if (i >= ET) return;
    int d = (i < NE) ? ei[NE + i] : (i - NE);
    atomicAdd(&deg[d], 1);
}

__global__ __launch_bounds__(256) void scanA(const int* __restrict__ deg,
                                             int* __restrict__ part, int* __restrict__ aux) {
    __shared__ int sh[256];
    int t = threadIdx.x;
    int i = blockIdx.x * 256 + t;
    int v = (i < NN) ? deg[i] : 0;
    sh[t] = v; __syncthreads();
    #pragma unroll
    for (int off = 1; off < 256; off <<= 1) {
        int u = (t >= off) ? sh[t - off] : 0;
        __syncthreads();
        sh[t] += u;
        __syncthreads();
    }
    if (i < NN) part[i] = sh[t];
    if (t == 255) aux[blockIdx.x] = sh[255];
}

__global__ __launch_bounds__(256) void scanB(const int* __restrict__ aux,
                                             int* __restrict__ auxex, int nb) {
    __shared__ int sh[256];
    int t = threadIdx.x;
    int v = (t < nb) ? aux[t] : 0;
    sh[t] = v; __syncthreads();
    #pragma unroll
    for (int off = 1; off < 256; off <<= 1) {
        int u = (t >= off) ? sh[t - off] : 0;
        __syncthreads();
        sh[t] += u;
        __syncthreads();
    }
    if (t < nb) auxex[t] = sh[t] - v;
}

__global__ void scanC(const int* __restrict__ part, const int* __restrict__ auxex,
                      int* __restrict__ rowptr) {
    int i = blockIdx.x * blockDim.x + threadIdx.x;
    if (i == 0) rowptr[0] = 0;
    if (i < NN) rowptr[i + 1] = part[i] + auxex[i >> 8];
}

__global__ void scatter_edges(const int* __restrict__ ei, const int* __restrict__ rowptr,
                              int* __restrict__ cur, int* __restrict__ srclist) {
    int i = blockIdx.x * blockDim.x + threadIdx.x;
    if (i >= ET) return;
    int s, d;
    if (i < NE) { s = ei[i]; d = ei[NE + i]; } else { s = d = i - NE; }
    int pos = rowptr[d] + atomicAdd(&cur[d], 1);
    srclist[pos] = s;
}

// ========== fused softmax + aggregate (bf16 h gather): wave per dst =========
__global__ __launch_bounds__(256) void gat_agg(
    const int* __restrict__ rowptr, const int* __restrict__ srclist,
    const float* __restrict__ a_s, const float* __restrict__ a_d,
    const unsigned short* __restrict__ h16, const float* __restrict__ bias,
    float* __restrict__ out)
{
    __shared__ __align__(16) uint2 ls[4][64];   // per-wave packed (coef, src)
    const int wv = threadIdx.x >> 6;
    int d = blockIdx.x * 4 + wv;
    if (d >= NN) return;
    int lane = threadIdx.x & 63;
    int s0 = rowptr[d], s1 = rowptr[d + 1];
    float ad = a_d[d];

    // phase 1: logits + wave max
    float earr[MAXK];
    int mysrc[MAXK];
    float mymax = -INFINITY;
    #pragma unroll
    for (int k = 0; k < MAXK; ++k) {
        int j = s0 + lane + k * 64;
        if (j < s1) {
            int s = srclist[j];
            mysrc[k] = s;
            float e = a_s[s] + ad;
            e = e > 0.f ? e : NEG * e;
            earr[k] = e;
            mymax = fmaxf(mymax, e);
        }
    }
    #pragma unroll
    for (int off = 32; off; off >>= 1)
        mymax = fmaxf(mymax, __shfl_xor(mymax, off));

    // phase 2: exp + wave sum
    float sum = 0.f;
    #pragma unroll
    for (int k = 0; k < MAXK; ++k) {
        int j = s0 + lane + k * 64;
        if (j < s1) {
            float w = __expf(earr[k] - mymax);
            earr[k] = w;
            sum += w;
        }
    }
    #pragma unroll
    for (int off = 32; off; off >>= 1)
        sum += __shfl_xor(sum, off);
    float invz = 1.f / (sum + 1e-16f);

    // phase 3: LDS-stashed (coef,src) pairs; 8-wide batched gathers for ILP
    const int li = (lane < 51) ? lane : 51;   // lanes >=52 read pad zeros
    float acc0 = 0.f, acc1 = 0.f;
    #pragma unroll
    for (int k = 0; k < MAXK; ++k) {
        int jb = s0 + k * 64;
        if (jb >= s1) break;
        int lim = s1 - jb; if (lim > 64) lim = 64;
        ls[wv][lane] = make_uint2(__float_as_uint(earr[k] * invz),
                                  (unsigned)mysrc[k]);   // wave-sync LDS exchange

        int i = 0;
        for (; i + 8 <= lim; i += 8) {
            uint4 q0 = *(const uint4*)&ls[wv][i];       // pairs i,   i+1
            uint4 q1 = *(const uint4*)&ls[wv][i + 2];   // pairs i+2, i+3
            uint4 q2 = *(const uint4*)&ls[wv][i + 4];
            uint4 q3 = *(const uint4*)&ls[wv][i + 6];
            unsigned v0 = *((const unsigned*)(h16 + (size_t)q0.y * HP) + li);
            unsigned v1 = *((const unsigned*)(h16 + (size_t)q0.w * HP) + li);
            unsigned v2 = *((const unsigned*)(h16 + (size_t)q1.y * HP) + li);
            unsigned v3 = *((const unsigned*)(h16 + (size_t)q1.w * HP) + li);
            unsigned v4 = *((const unsigned*)(h16 + (size_t)q2.y * HP) + li);
            unsigned v5 = *((const unsigned*)(h16 + (size_t)q2.w * HP) + li);
            unsigned v6 = *((const unsigned*)(h16 + (size_t)q3.y * HP) + li);
            unsigned v7 = *((const unsigned*)(h16 + (size_t)q3.w * HP) + li);
            float c0 = __uint_as_float(q0.x), c1 = __uint_as_float(q0.z);
            float c2 = __uint_as_float(q1.x), c3 = __uint_as_float(q1.z);
            float c4 = __uint_as_float(q2.x), c5 = __uint_as_float(q2.z);
            float c6 = __uint_as_float(q3.x), c7 = __uint_as_float(q3.z);
            acc0 = fmaf(c0, bflo(v0), acc0); acc1 = fmaf(c0, bfhi(v0), acc1);
            acc0 = fmaf(c1, bflo(v1), acc0); acc1 = fmaf(c1, bfhi(v1), acc1);
            acc0 = fmaf(c2, bflo(v2), acc0); acc1 = fmaf(c2, bfhi(v2), acc1);
            acc0 = fmaf(c3, bflo(v3), acc0); acc1 = fmaf(c3, bfhi(v3), acc1);
            acc0 = fmaf(c4, bflo(v4), acc0); acc1 = fmaf(c4, bfhi(v4), acc1);
            acc0 = fmaf(c5, bflo(v5), acc0); acc1 = fmaf(c5, bfhi(v5), acc1);
            acc0 = fmaf(c6, bflo(v6), acc0); acc1 = fmaf(c6, bfhi(v6), acc1);
            acc0 = fmaf(c7, bflo(v7), acc0); acc1 = fmaf(c7, bfhi(v7), acc1);
        }
        for (; i + 4 <= lim; i += 4) {
            uint4 q0 = *(const uint4*)&ls[wv][i];
            uint4 q1 = *(const uint4*)&ls[wv][i + 2];
            unsigned v0 = *((const unsigned*)(h16 + (size_t)q0.y * HP) + li);
            unsigned v1 = *((const unsigned*)(h16 + (size_t)q0.w * HP) + li);
            unsigned v2 = *((const unsigned*)(h16 + (size_t)q1.y * HP) + li);
            unsigned v3 = *((const unsigned*)(h16 + (size_t)q1.w * HP) + li);
            float c0 = __uint_as_float(q0.x), c1 = __uint_as_float(q0.z);
            float c2 = __uint_as_float(q1.x), c3 = __uint_as_float(q1.z);
            acc0 = fmaf(c0, bflo(v0), acc0); acc1 = fmaf(c0, bfhi(v0), acc1);
            acc0 = fmaf(c1, bflo(v1), acc0); acc1 = fmaf(c1, bfhi(v1), acc1);
            acc0 = fmaf(c2, bflo(v2), acc0); acc1 = fmaf(c2, bfhi(v2), acc1);
            acc0 = fmaf(c3, bflo(v3), acc0); acc1 = fmaf(c3, bfhi(v3), acc1);
        }
        for (; i < lim; ++i) {
            uint2 p = ls[wv][i];
            unsigned v = *((const unsigned*)(h16 + (size_t)p.y * HP) + li);
            float c = __uint_as_float(p.x);
            acc0 = fmaf(c, bflo(v), acc0);
            acc1 = fmaf(c, bfhi(v), acc1);
        }
    }
    int c0 = 2 * lane;
    if (c0 < DF)     out[(size_t)d * DF + c0]     = acc0 + bias[c0];
    if (c0 + 1 < DF) out[(size_t)d * DF + c0 + 1] = acc1 + bias[c0 + 1];
}

static inline size_t alignup(size_t v) { return (v + 255) & ~size_t(255); }

extern "C" void kernel_launch(void* const* d_in, const int* in_sizes, int n_in,
                              void* d_out, int out_size, void* d_ws, size_t ws_size,
                              hipStream_t stream)
{
    const float* x    = (const float*)d_in[0];
    const int*   ei   = (const int*)  d_in[1];   // [2, NE]
    const float* Ws   = (const float*)d_in[2];   // [L, D, D]
    const float* a_s  = (const float*)d_in[3];   // [L, D]
    const float* a_d  = (const float*)d_in[4];   // [L, D]
    const float* bias = (const float*)d_in[5];   // [L, D]
    float* out = (float*)d_out;

    char* w = (char*)d_ws;
    unsigned short* h16 = (unsigned short*)w; w += alignup((size_t)NN * HP * 2);
    float* x1      = (float*)w; w += alignup((size_t)NN * DF * 4);
    int*   srclist = (int*)w;   w += alignup((size_t)ET * 4);
    float* as_n    = (float*)w; w += alignup((size_t)NN * 4);
    float* ad_n    = (float*)w; w += alignup((size_t)NN * 4);
    int*   deg     = (int*)w;   w += alignup((size_t)NN * 4);
    int*   part    = (int*)w;   w += alignup((size_t)NN * 4);
    int*   cur     = (int*)w;   w += alignup((size_t)NN * 4);
    int*   rowptr  = (int*)w;   w += alignup((size_t)(NN + 1) * 4);
    int*   aux     = (int*)w;   w += alignup(256 * 4);
    int*   auxex   = (int*)w;   w += alignup(256 * 4);
    float* wa_s    = (float*)w; w += alignup(DF * 4);
    float* wa_d    = (float*)w; w += alignup(DF * 4);

    const int NB = (NN + 255) / 256;   // 196 scan blocks

    hipMemsetAsync(deg, 0, (size_t)NN * 4, stream);
    hipMemsetAsync(cur, 0, (size_t)NN * 4, stream);
    count_deg<<<(ET + 255) / 256, 256, 0, stream>>>(ei, deg);
    scanA<<<NB, 256, 0, stream>>>(deg, part, aux);
    scanB<<<1, 256, 0, stream>>>(aux, auxex, NB);
    scanC<<<NB, 256, 0, stream>>>(part, auxex, rowptr);
    scatter_edges<<<(ET + 255) / 256, 256, 0, stream>>>(ei, rowptr, cur, srclist);

    for (int l = 0; l < 2; ++l) {
        const float* curx = (l == 0) ? x : x1;
        float*       nxt  = (l == 0) ? x1 : out;
        const float* Wl   = Ws + l * DF * DF;

        proj_a<<<(DF + 3) / 4, 256, 0, stream>>>(Wl, a_s + l * DF, a_d + l * DF,
                                                 wa_s, wa_d);
        alpha_n<<<(NN + 3) / 4, 256, 0, stream>>>(curx, wa_s, wa_d, as_n, ad_n);
        gemm_h<<<(NN + BM - 1) / BM, 256, 0, stream>>>(curx, Wl, h16);
        gat_agg<<<(NN + 3) / 4, 256, 0, stream>>>(rowptr, srclist, as_n, ad_n,
                                                  h16, bias + l * DF, nxt);
    }
}

// Round 13
// 302.588 us; speedup vs baseline: 4.1428x; 1.1658x over previous
//
#include <hip/hip_runtime.h>
#include <math.h>

#define NN 50000
#define NE 800000
#define ET (NE + NN)     // edges + self-loops
#define DF 101
#define HP 104           // padded bf16 row stride (52 uints, 4B-aligned)
#define NEG 0.2f
#define MAXK 8           // gat_agg: supports in-degree up to 8*64=512

// MFMA gemm tiling
#define GM 64            // rows per block
#define KP 128           // K padded (101 -> 128)
#define NP 112           // N padded (101 -> 112, 7 tiles of 16)
#define LSTR 136         // LDS row stride in ushorts (128 + 8 pad)

typedef __attribute__((ext_vector_type(8))) short bf16x8;
typedef __attribute__((ext_vector_type(4))) float f32x4;

// float -> bf16 round-to-nearest-even
__device__ __forceinline__ unsigned short f2bf(float f) {
    unsigned u = __float_as_uint(f);
    unsigned r = u + 0x7FFFu + ((u >> 16) & 1u);
    return (unsigned short)(r >> 16);
}
__device__ __forceinline__ float bflo(unsigned v) { return __uint_as_float(v << 16); }
__device__ __forceinline__ float bfhi(unsigned v) { return __uint_as_float(v & 0xFFFF0000u); }

// ---- wa = W @ a  (per-layer, 101-vectors); wave per output row k ----
__global__ __launch_bounds__(256) void proj_a(
    const float* __restrict__ W, const float* __restrict__ a_s,
    const float* __restrict__ a_d,
    float* __restrict__ wa_s, float* __restrict__ wa_d)
{
    int k = blockIdx.x * 4 + (threadIdx.x >> 6);
    if (k >= DF) return;
    int lane = threadIdx.x & 63;
    const float* wr = W + (size_t)k * DF;
    float w0 = wr[lane];
    float w1 = (lane < DF - 64) ? wr[64 + lane] : 0.f;
    float s1 = (lane < DF - 64) ? a_s[64 + lane] : 0.f;
    float d1 = (lane < DF - 64) ? a_d[64 + lane] : 0.f;
    float ps = w0 * a_s[lane] + w1 * s1;
    float pd = w0 * a_d[lane] + w1 * d1;
    #pragma unroll
    for (int off = 32; off; off >>= 1) {
        ps += __shfl_xor(ps, off);
        pd += __shfl_xor(pd, off);
    }
    if (lane == 0) { wa_s[k] = ps; wa_d[k] = pd; }
}

// ---- alpha_s[n] = x[n]·wa_s, alpha_d[n] = x[n]·wa_d; wave per node ----
__global__ __launch_bounds__(256) void alpha_n(
    const float* __restrict__ x, const float* __restrict__ wa_s,
    const float* __restrict__ wa_d,
    float* __restrict__ as_n, float* __restrict__ ad_n)
{
    int n = blockIdx.x * 4 + (threadIdx.x >> 6);
    if (n >= NN) return;
    int lane = threadIdx.x & 63;
    const float* xr = x + (size_t)n * DF;
    float x0 = xr[lane];
    float x1v = (lane < DF - 64) ? xr[64 + lane] : 0.f;
    float s1  = (lane < DF - 64) ? wa_s[64 + lane] : 0.f;
    float d1  = (lane < DF - 64) ? wa_d[64 + lane] : 0.f;
    float ps = x0 * wa_s[lane] + x1v * s1;
    float pd = x0 * wa_d[lane] + x1v * d1;
    #pragma unroll
    for (int off = 32; off; off >>= 1) {
        ps += __shfl_xor(ps, off);
        pd += __shfl_xor(pd, off);
    }
    if (lane == 0) { as_n[n] = ps; ad_n[n] = pd; }
}

// ---- prep: Wt bf16 [NP][KP], transposed + zero-padded ----
__global__ void prep_wt(const float* __restrict__ W, unsigned short* __restrict__ wtb) {
    int i = blockIdx.x * 256 + threadIdx.x;
    if (i >= NP * KP) return;
    int c = i >> 7;          // output col (N)
    int k = i & (KP - 1);
    float v = (c < DF && k < DF) ? W[k * DF + c] : 0.f;
    wtb[c * KP + k] = f2bf(v);
}

// ---- h16 = bf16(x @ W) via MFMA 16x16x32: block = 64 rows, 4 waves ----
__global__ __launch_bounds__(256) void gemm_h(
    const float* __restrict__ x, const unsigned short* __restrict__ wtb,
    unsigned short* __restrict__ h16)
{
    __shared__ unsigned short xs[GM * LSTR];   // 17408 B
    __shared__ unsigned short ws[NP * LSTR];   // 30464 B
    const int t = threadIdx.x;
    const int row0 = blockIdx.x * GM;

    // stage Wt (bf16, linear rows of 128 -> padded LDS rows)
    {
        const uint4* src = (const uint4*)wtb;           // [NP][16] uint4
        for (int i = t; i < NP * 16; i += 256) {
            int r = i >> 4, seg = i & 15;
            uint4 v = src[r * 16 + seg];
            *(uint4*)&ws[r * LSTR + seg * 8] = v;
        }
    }
    // stage x tile, f32 -> bf16, zero pad (k>=DF or row>=NN)
    for (int i = t; i < GM * KP; i += 256) {
        int r = i >> 7, k = i & (KP - 1);
        int row = row0 + r;
        float v = (k < DF && row < NN) ? x[(size_t)row * DF + k] : 0.f;
        xs[r * LSTR + k] = f2bf(v);
    }
    __syncthreads();

    const int wv = t >> 6, lane = t & 63;
    const int arow = wv * 16 + (lane & 15);
    const int kgrp = (lane >> 4) * 8;

    bf16x8 a[4];
    #pragma unroll
    for (int ks = 0; ks < 4; ++ks)
        a[ks] = *(const bf16x8*)&xs[arow * LSTR + ks * 32 + kgrp];

    #pragma unroll
    for (int nt = 0; nt < 7; ++nt) {
        f32x4 acc = {0.f, 0.f, 0.f, 0.f};
        const int col = nt * 16 + (lane & 15);
        #pragma unroll
        for (int ks = 0; ks < 4; ++ks) {
            bf16x8 b = *(const bf16x8*)&ws[col * LSTR + ks * 32 + kgrp];
            acc = __builtin_amdgcn_mfma_f32_16x16x32_bf16(a[ks], b, acc, 0, 0, 0);
        }
        const int rbase = row0 + wv * 16 + (lane >> 4) * 4;
        #pragma unroll
        for (int r = 0; r < 4; ++r) {
            int row = rbase + r;
            if (col < HP && row < NN)                      // cols 101..103 are 0
                h16[(size_t)row * HP + col] = f2bf(acc[r]);
        }
    }
}

// ================= CSR build (once per launch; reused by both layers) =======

__global__ void count_rank(const int* __restrict__ ei, int* __restrict__ deg,
                           unsigned short* __restrict__ rank) {
    int i = blockIdx.x * blockDim.x + threadIdx.x;
    if (i >= ET) return;
    int d = (i < NE) ? ei[NE + i] : (i - NE);
    rank[i] = (unsigned short)atomicAdd(&deg[d], 1);
}

__global__ __launch_bounds__(256) void scanA(const int* __restrict__ deg,
                                             int* __restrict__ part, int* __restrict__ aux) {
    __shared__ int sh[256];
    int t = threadIdx.x;
    int i = blockIdx.x * 256 + t;
    int v = (i < NN) ? deg[i] : 0;
    sh[t] = v; __syncthreads();
    #pragma unroll
    for (int off = 1; off < 256; off <<= 1) {
        int u = (t >= off) ? sh[t - off] : 0;
        __syncthreads();
        sh[t] += u;
        __syncthreads();
    }
    if (i < NN) part[i] = sh[t];
    if (t == 255) aux[blockIdx.x] = sh[255];
}

__global__ __launch_bounds__(256) void scanB(const int* __restrict__ aux,
                                             int* __restrict__ auxex, int nb) {
    __shared__ int sh[256];
    int t = threadIdx.x;
    int v = (t < nb) ? aux[t] : 0;
    sh[t] = v; __syncthreads();
    #pragma unroll
    for (int off = 1; off < 256; off <<= 1) {
        int u = (t >= off) ? sh[t - off] : 0;
        __syncthreads();
        sh[t] += u;
        __syncthreads();
    }
    if (t < nb) auxex[t] = sh[t] - v;
}

__global__ void scanC(const int* __restrict__ part, const int* __restrict__ auxex,
                      int* __restrict__ rowptr) {
    int i = blockIdx.x * blockDim.x + threadIdx.x;
    if (i == 0) rowptr[0] = 0;
    if (i < NN) rowptr[i + 1] = part[i] + auxex[i >> 8];
}

__global__ void scatter_plain(const int* __restrict__ ei, const int* __restrict__ rowptr,
                              const unsigned short* __restrict__ rank,
                              int* __restrict__ srclist) {
    int i = blockIdx.x * blockDim.x + threadIdx.x;
    if (i >= ET) return;
    int s, d;
    if (i < NE) { s = ei[i]; d = ei[NE + i]; } else { s = d = i - NE; }
    srclist[rowptr[d] + rank[i]] = s;     // no atomic, no dependent chain
}

// ========== fused softmax + aggregate (bf16 h gather): wave per dst =========
__global__ __launch_bounds__(256) void gat_agg(
    const int* __restrict__ rowptr, const int* __restrict__ srclist,
    const float* __restrict__ a_s, const float* __restrict__ a_d,
    const unsigned short* __restrict__ h16, const float* __restrict__ bias,
    float* __restrict__ out)
{
    __shared__ __align__(16) uint2 ls[4][64];   // per-wave packed (coef, src)
    const int wv = threadIdx.x >> 6;
    int d = blockIdx.x * 4 + wv;
    if (d >= NN) return;
    int lane = threadIdx.x & 63;
    int s0 = rowptr[d], s1 = rowptr[d + 1];
    float ad = a_d[d];

    float earr[MAXK];
    int mysrc[MAXK];
    float mymax = -INFINITY;
    #pragma unroll
    for (int k = 0; k < MAXK; ++k) {
        int j = s0 + lane + k * 64;
        if (j < s1) {
            int s = srclist[j];
            mysrc[k] = s;
            float e = a_s[s] + ad;
            e = e > 0.f ? e : NEG * e;
            earr[k] = e;
            mymax = fmaxf(mymax, e);
        }
    }
    #pragma unroll
    for (int off = 32; off; off >>= 1)
        mymax = fmaxf(mymax, __shfl_xor(mymax, off));

    float sum = 0.f;
    #pragma unroll
    for (int k = 0; k < MAXK; ++k) {
        int j = s0 + lane + k * 64;
        if (j < s1) {
            float w = __expf(earr[k] - mymax);
            earr[k] = w;
            sum += w;
        }
    }
    #pragma unroll
    for (int off = 32; off; off >>= 1)
        sum += __shfl_xor(sum, off);
    float invz = 1.f / (sum + 1e-16f);

    const int li = (lane < 51) ? lane : 51;   // lanes >=52 read pad zeros
    float acc0 = 0.f, acc1 = 0.f;
    #pragma unroll
    for (int k = 0; k < MAXK; ++k) {
        int jb = s0 + k * 64;
        if (jb >= s1) break;
        int lim = s1 - jb; if (lim > 64) lim = 64;
        ls[wv][lane] = make_uint2(__float_as_uint(earr[k] * invz),
                                  (unsigned)mysrc[k]);   // wave-sync LDS exchange

        int i = 0;
        for (; i + 8 <= lim; i += 8) {
            uint4 q0 = *(const uint4*)&ls[wv][i];
            uint4 q1 = *(const uint4*)&ls[wv][i + 2];
            uint4 q2 = *(const uint4*)&ls[wv][i + 4];
            uint4 q3 = *(const uint4*)&ls[wv][i + 6];
            unsigned v0 = *((const unsigned*)(h16 + (size_t)q0.y * HP) + li);
            unsigned v1 = *((const unsigned*)(h16 + (size_t)q0.w * HP) + li);
            unsigned v2 = *((const unsigned*)(h16 + (size_t)q1.y * HP) + li);
            unsigned v3 = *((const unsigned*)(h16 + (size_t)q1.w * HP) + li);
            unsigned v4 = *((const unsigned*)(h16 + (size_t)q2.y * HP) + li);
            unsigned v5 = *((const unsigned*)(h16 + (size_t)q2.w * HP) + li);
            unsigned v6 = *((const unsigned*)(h16 + (size_t)q3.y * HP) + li);
            unsigned v7 = *((const unsigned*)(h16 + (size_t)q3.w * HP) + li);
            float c0 = __uint_as_float(q0.x), c1 = __uint_as_float(q0.z);
            float c2 = __uint_as_float(q1.x), c3 = __uint_as_float(q1.z);
            float c4 = __uint_as_float(q2.x), c5 = __uint_as_float(q2.z);
            float c6 = __uint_as_float(q3.x), c7 = __uint_as_float(q3.z);
            acc0 = fmaf(c0, bflo(v0), acc0); acc1 = fmaf(c0, bfhi(v0), acc1);
            acc0 = fmaf(c1, bflo(v1), acc0); acc1 = fmaf(c1, bfhi(v1), acc1);
            acc0 = fmaf(c2, bflo(v2), acc0); acc1 = fmaf(c2, bfhi(v2), acc1);
            acc0 = fmaf(c3, bflo(v3), acc0); acc1 = fmaf(c3, bfhi(v3), acc1);
            acc0 = fmaf(c4, bflo(v4), acc0); acc1 = fmaf(c4, bfhi(v4), acc1);
            acc0 = fmaf(c5, bflo(v5), acc0); acc1 = fmaf(c5, bfhi(v5), acc1);
            acc0 = fmaf(c6, bflo(v6), acc0); acc1 = fmaf(c6, bfhi(v6), acc1);
            acc0 = fmaf(c7, bflo(v7), acc0); acc1 = fmaf(c7, bfhi(v7), acc1);
        }
        for (; i + 4 <= lim; i += 4) {
            uint4 q0 = *(const uint4*)&ls[wv][i];
            uint4 q1 = *(const uint4*)&ls[wv][i + 2];
            unsigned v0 = *((const unsigned*)(h16 + (size_t)q0.y * HP) + li);
            unsigned v1 = *((const unsigned*)(h16 + (size_t)q0.w * HP) + li);
            unsigned v2 = *((const unsigned*)(h16 + (size_t)q1.y * HP) + li);
            unsigned v3 = *((const unsigned*)(h16 + (size_t)q1.w * HP) + li);
            float c0 = __uint_as_float(q0.x), c1 = __uint_as_float(q0.z);
            float c2 = __uint_as_float(q1.x), c3 = __uint_as_float(q1.z);
            acc0 = fmaf(c0, bflo(v0), acc0); acc1 = fmaf(c0, bfhi(v0), acc1);
            acc0 = fmaf(c1, bflo(v1), acc0); acc1 = fmaf(c1, bfhi(v1), acc1);
            acc0 = fmaf(c2, bflo(v2), acc0); acc1 = fmaf(c2, bfhi(v2), acc1);
            acc0 = fmaf(c3, bflo(v3), acc0); acc1 = fmaf(c3, bfhi(v3), acc1);
        }
        for (; i < lim; ++i) {
            uint2 p = ls[wv][i];
            unsigned v = *((const unsigned*)(h16 + (size_t)p.y * HP) + li);
            float c = __uint_as_float(p.x);
            acc0 = fmaf(c, bflo(v), acc0);
            acc1 = fmaf(c, bfhi(v), acc1);
        }
    }
    int c0 = 2 * lane;
    if (c0 < DF)     out[(size_t)d * DF + c0]     = acc0 + bias[c0];
    if (c0 + 1 < DF) out[(size_t)d * DF + c0 + 1] = acc1 + bias[c0 + 1];
}

static inline size_t alignup(size_t v) { return (v + 255) & ~size_t(255); }

extern "C" void kernel_launch(void* const* d_in, const int* in_sizes, int n_in,
                              void* d_out, int out_size, void* d_ws, size_t ws_size,
                              hipStream_t stream)
{
    const float* x    = (const float*)d_in[0];
    const int*   ei   = (const int*)  d_in[1];   // [2, NE]
    const float* Ws   = (const float*)d_in[2];   // [L, D, D]
    const float* a_s  = (const float*)d_in[3];   // [L, D]
    const float* a_d  = (const float*)d_in[4];   // [L, D]
    const float* bias = (const float*)d_in[5];   // [L, D]
    float* out = (float*)d_out;

    char* w = (char*)d_ws;
    unsigned short* h16  = (unsigned short*)w; w += alignup((size_t)NN * HP * 2);
    float* x1      = (float*)w; w += alignup((size_t)NN * DF * 4);
    int*   srclist = (int*)w;   w += alignup((size_t)ET * 4);
    unsigned short* rank = (unsigned short*)w; w += alignup((size_t)ET * 2);
    unsigned short* wtb0 = (unsigned short*)w; w += alignup((size_t)NP * KP * 2);
    unsigned short* wtb1 = (unsigned short*)w; w += alignup((size_t)NP * KP * 2);
    float* as_n    = (float*)w; w += alignup((size_t)NN * 4);
    float* ad_n    = (float*)w; w += alignup((size_t)NN * 4);
    int*   deg     = (int*)w;   w += alignup((size_t)NN * 4);
    int*   part    = (int*)w;   w += alignup((size_t)NN * 4);
    int*   rowptr  = (int*)w;   w += alignup((size_t)(NN + 1) * 4);
    int*   aux     = (int*)w;   w += alignup(256 * 4);
    int*   auxex   = (int*)w;   w += alignup(256 * 4);
    float* wa_s    = (float*)w; w += alignup(DF * 4);
    float* wa_d    = (float*)w; w += alignup(DF * 4);

    const int NB = (NN + 255) / 256;   // 196 scan blocks
    const int NWT = (NP * KP + 255) / 256;

    // weight prep (layer-independent of node data)
    prep_wt<<<NWT, 256, 0, stream>>>(Ws,               wtb0);
    prep_wt<<<NWT, 256, 0, stream>>>(Ws + DF * DF,     wtb1);

    // CSR build: rank-recording count, scan, atomic-free scatter
    hipMemsetAsync(deg, 0, (size_t)NN * 4, stream);
    count_rank<<<(ET + 255) / 256, 256, 0, stream>>>(ei, deg, rank);
    scanA<<<NB, 256, 0, stream>>>(deg, part, aux);
    scanB<<<1, 256, 0, stream>>>(aux, auxex, NB);
    scanC<<<NB, 256, 0, stream>>>(part, auxex, rowptr);
    scatter_plain<<<(ET + 255) / 256, 256, 0, stream>>>(ei, rowptr, rank, srclist);

    for (int l = 0; l < 2; ++l) {
        const float* curx = (l == 0) ? x : x1;
        float*       nxt  = (l == 0) ? x1 : out;
        const float* Wl   = Ws + l * DF * DF;
        const unsigned short* wtb = (l == 0) ? wtb0 : wtb1;

        proj_a<<<(DF + 3) / 4, 256, 0, stream>>>(Wl, a_s + l * DF, a_d + l * DF,
                                                 wa_s, wa_d);
        alpha_n<<<(NN + 3) / 4, 256, 0, stream>>>(curx, wa_s, wa_d, as_n, ad_n);
        gemm_h<<<(NN + GM - 1) / GM, 256, 0, stream>>>(curx, wtb, h16);
        gat_agg<<<(NN + 3) / 4, 256, 0, stream>>>(rowptr, srclist, as_n, ad_n,
                                                  h16, bias + l * DF, nxt);
    }
}